// Round 3
// baseline (1574.811 us; speedup 1.0000x reference)
//
#include <hip/hip_runtime.h>

// ---------------------------------------------------------------- types
typedef unsigned short u16;
typedef __attribute__((ext_vector_type(8))) unsigned short ushortx8;
typedef __attribute__((ext_vector_type(4))) unsigned short ushortx4;
typedef __attribute__((ext_vector_type(8))) short short8;
typedef __attribute__((ext_vector_type(4))) float fx4;

__device__ __forceinline__ float bf2f(u16 v) {
    union { unsigned int u; float f; } x; x.u = ((unsigned int)v) << 16; return x.f;
}
__device__ __forceinline__ u16 f2bf(float f) {
    union { float f; unsigned int u; } x; x.f = f;
    unsigned int r = x.u + 0x7fffu + ((x.u >> 16) & 1u);
    return (u16)(r >> 16);
}

// ---------------------------------------------------------------- sizes
#define TSEQ 1024
#define DMOD 1024
#define NH   16
#define DH   64
#define NE   8
#define DFF  4096

// ---------------------------------------------------------------- ws layout (bytes), total ~78.5MB
// hbuf overlays the attention-phase buffers (disjoint lifetimes).
#define H_OFF    ((size_t)0)                        // u16 8x1024x4096 (64MB), moe1->moe2 only
#define XH_OFF   ((size_t)0)                        // u16 1M : LN1 out hi
#define XL_OFF   ((size_t)2  << 20)                 // u16 1M : LN1 out lo
#define Q_OFF    ((size_t)4  << 20)                 // f32 1M
#define K_OFF    ((size_t)8  << 20)                 // f32 1M
#define V_OFF    ((size_t)12 << 20)                 // f32 1M
#define AH_OFF   ((size_t)16 << 20)                 // u16 1M : attn out hi
#define AL_OFF   ((size_t)18 << 20)                 // u16 1M : attn out lo
#define E2_OFF   ((size_t)64 << 20)                 // f32 1M : emb2
#define Y32_OFF  ((size_t)68 << 20)                 // f32 1M : LN2 out fp32
#define YBF_OFF  ((size_t)72 << 20)                 // u16 1M : LN2 out bf16
#define MOE_OFF  ((size_t)74 << 20)                 // f32 1M : moe accumulator
#define W_OFF    ((size_t)78 << 20)                 // f32 1024x8
#define CNT_OFF  (((size_t)78 << 20) + 64*1024)     // int 8
#define LIST_OFF (((size_t)78 << 20) + 128*1024)    // int 8x1024
#define GATE_OFF (((size_t)78 << 20) + 192*1024)    // f32 8x1024

// ================================================================ LayerNorm 1 -> hi/lo bf16
__global__ __launch_bounds__(256) void ln1_kernel(
    const float* __restrict__ in, const float* __restrict__ gamma,
    const float* __restrict__ beta, u16* __restrict__ xh, u16* __restrict__ xl)
{
    __shared__ float rs[4], rs2[4];
    const int row = blockIdx.x, tid = threadIdx.x;
    fx4 v = *(const fx4*)(in + (size_t)row * DMOD + tid * 4);
    float s = 0.f, s2 = 0.f;
#pragma unroll
    for (int j = 0; j < 4; j++) { s += v[j]; s2 += v[j] * v[j]; }
#pragma unroll
    for (int off = 32; off; off >>= 1) { s += __shfl_down(s, off); s2 += __shfl_down(s2, off); }
    if ((tid & 63) == 0) { rs[tid >> 6] = s; rs2[tid >> 6] = s2; }
    __syncthreads();
    float S = rs[0] + rs[1] + rs[2] + rs[3];
    float S2 = rs2[0] + rs2[1] + rs2[2] + rs2[3];
    float mean = S * (1.f / DMOD);
    float var  = S2 * (1.f / DMOD) - mean * mean;
    float inv = rsqrtf(var + 1e-6f);
    fx4 gv = *(const fx4*)(gamma + tid * 4);
    fx4 bv = *(const fx4*)(beta + tid * 4);
    ushortx4 oh, ol;
#pragma unroll
    for (int j = 0; j < 4; j++) {
        float r = (v[j] - mean) * inv * gv[j] + bv[j];
        u16 h = f2bf(r);
        oh[j] = h; ol[j] = f2bf(r - bf2f(h));
    }
    *(ushortx4*)(xh + (size_t)row * DMOD + tid * 4) = oh;
    *(ushortx4*)(xl + (size_t)row * DMOD + tid * 4) = ol;
}

// LN2: f32 in -> f32 (router) + bf16 (MoE GEMM A)
__global__ __launch_bounds__(256) void ln2_kernel(
    const float* __restrict__ in, const float* __restrict__ gamma,
    const float* __restrict__ beta, float* __restrict__ y32, u16* __restrict__ ybf)
{
    __shared__ float rs[4], rs2[4];
    const int row = blockIdx.x, tid = threadIdx.x;
    fx4 v = *(const fx4*)(in + (size_t)row * DMOD + tid * 4);
    float s = 0.f, s2 = 0.f;
#pragma unroll
    for (int j = 0; j < 4; j++) { s += v[j]; s2 += v[j] * v[j]; }
#pragma unroll
    for (int off = 32; off; off >>= 1) { s += __shfl_down(s, off); s2 += __shfl_down(s2, off); }
    if ((tid & 63) == 0) { rs[tid >> 6] = s; rs2[tid >> 6] = s2; }
    __syncthreads();
    float S = rs[0] + rs[1] + rs[2] + rs[3];
    float S2 = rs2[0] + rs2[1] + rs2[2] + rs2[3];
    float mean = S * (1.f / DMOD);
    float var  = S2 * (1.f / DMOD) - mean * mean;
    float inv = rsqrtf(var + 1e-6f);
    fx4 gv = *(const fx4*)(gamma + tid * 4);
    fx4 bv = *(const fx4*)(beta + tid * 4);
    fx4 o32; ushortx4 o;
#pragma unroll
    for (int j = 0; j < 4; j++) {
        float r = (v[j] - mean) * inv * gv[j] + bv[j];
        o32[j] = r; o[j] = f2bf(r);
    }
    *(fx4*)(y32 + (size_t)row * DMOD + tid * 4) = o32;
    *(ushortx4*)(ybf + (size_t)row * DMOD + tid * 4) = o;
}

// ================================================================ GEMM mainloops (64x64 tile, 4 waves)
#define LDA_S 40

// plain bf16 (MoE): A bf16[M][K] (aptr per-thread base; null -> 0), B fp32[K][N]
__device__ __forceinline__ void gemm64_loop(
    fx4 acc[4], const u16* aptr, const float* __restrict__ B, size_t boff,
    int ldb, int K, u16* As, u16* Bs, int tid)
{
    const int wave = tid >> 6, lane = tid & 63, quad = lane >> 4, l16 = lane & 15;
    const int ar = tid >> 2, ak = (tid & 3) * 8;
    for (int k0 = 0; k0 < K; k0 += 32) {
        __syncthreads();
        ushortx8 av;
#pragma unroll
        for (int j = 0; j < 8; j++) av[j] = 0;
        if (aptr) av = *(const ushortx8*)(aptr + k0);
        *(ushortx8*)(&As[ar * LDA_S + ak]) = av;
        ushortx8 bv;
#pragma unroll
        for (int j = 0; j < 8; j++) bv[j] = f2bf(B[boff + (size_t)(k0 + j) * ldb]);
        *(ushortx8*)(&Bs[(tid & 63) * LDA_S + (tid >> 6) * 8]) = bv;
        __syncthreads();
        short8 af = *(const short8*)(&As[(wave * 16 + l16) * LDA_S + quad * 8]);
#pragma unroll
        for (int s = 0; s < 4; s++) {
            short8 bf_ = *(const short8*)(&Bs[(s * 16 + l16) * LDA_S + quad * 8]);
            acc[s] = __builtin_amdgcn_mfma_f32_16x16x32_bf16(af, bf_, acc[s], 0, 0, 0);
        }
    }
}

// hi/lo (Markidis): acc += Ah*Bh + Ah*Bl + Al*Bh  -> ~2^-18 rel error
__device__ __forceinline__ void gemm64_hilo(
    fx4 acc[4], const u16* ahi, const u16* alo, const float* __restrict__ B, size_t boff,
    int ldb, int K, u16* AsH, u16* AsL, u16* BsH, u16* BsL, int tid)
{
    const int wave = tid >> 6, lane = tid & 63, quad = lane >> 4, l16 = lane & 15;
    const int ar = tid >> 2, ak = (tid & 3) * 8;
    for (int k0 = 0; k0 < K; k0 += 32) {
        __syncthreads();
        *(ushortx8*)(&AsH[ar * LDA_S + ak]) = *(const ushortx8*)(ahi + k0);
        *(ushortx8*)(&AsL[ar * LDA_S + ak]) = *(const ushortx8*)(alo + k0);
        ushortx8 bh, bl;
#pragma unroll
        for (int j = 0; j < 8; j++) {
            float w = B[boff + (size_t)(k0 + j) * ldb];
            u16 hh = f2bf(w);
            bh[j] = hh; bl[j] = f2bf(w - bf2f(hh));
        }
        *(ushortx8*)(&BsH[(tid & 63) * LDA_S + (tid >> 6) * 8]) = bh;
        *(ushortx8*)(&BsL[(tid & 63) * LDA_S + (tid >> 6) * 8]) = bl;
        __syncthreads();
        short8 ah = *(const short8*)(&AsH[(wave * 16 + l16) * LDA_S + quad * 8]);
        short8 al = *(const short8*)(&AsL[(wave * 16 + l16) * LDA_S + quad * 8]);
#pragma unroll
        for (int s = 0; s < 4; s++) {
            short8 bhf = *(const short8*)(&BsH[(s * 16 + l16) * LDA_S + quad * 8]);
            short8 blf = *(const short8*)(&BsL[(s * 16 + l16) * LDA_S + quad * 8]);
            acc[s] = __builtin_amdgcn_mfma_f32_16x16x32_bf16(ah, blf, acc[s], 0, 0, 0);
            acc[s] = __builtin_amdgcn_mfma_f32_16x16x32_bf16(al, bhf, acc[s], 0, 0, 0);
            acc[s] = __builtin_amdgcn_mfma_f32_16x16x32_bf16(ah, bhf, acc[s], 0, 0, 0);
        }
    }
}

// ================================================================ QKV projection (hi/lo)
__global__ __launch_bounds__(256) void qkv_kernel(
    const u16* __restrict__ xh, const u16* __restrict__ xl,
    const float* __restrict__ WQ, const float* __restrict__ WK, const float* __restrict__ WV,
    float* __restrict__ Qf, float* __restrict__ Kf, float* __restrict__ Vf)
{
    __shared__ u16 AsH[64 * LDA_S], AsL[64 * LDA_S], BsH[64 * LDA_S], BsL[64 * LDA_S];
    const int tid = threadIdx.x;
    const int mt = blockIdx.x, h = blockIdx.y, z = blockIdx.z;
    const float* W = (z == 0) ? WQ : (z == 1) ? WK : WV;
    float* Out = (z == 0) ? Qf : (z == 1) ? Kf : Vf;
    const int m0 = mt * 64;
    const size_t aoff = (size_t)(m0 + (tid >> 2)) * DMOD + (tid & 3) * 8;
    size_t boff = (size_t)h * (DMOD * DH) + (size_t)((tid >> 6) * 8) * DH + (tid & 63);
    fx4 acc[4] = {};
    gemm64_hilo(acc, xh + aoff, xl + aoff, W, boff, DH, DMOD, AsH, AsL, BsH, BsL, tid);
    const int wave = tid >> 6, lane = tid & 63, quad = lane >> 4, l16 = lane & 15;
    float* ob = Out + (size_t)h * (TSEQ * DH);
#pragma unroll
    for (int s = 0; s < 4; s++)
#pragma unroll
        for (int r = 0; r < 4; r++) {
            int row = m0 + wave * 16 + quad * 4 + r;
            int col = s * 16 + l16;
            ob[(size_t)row * DH + col] = acc[s][r];
        }
}

// ================================================================ RoPE (matched-precision trig)
__global__ __launch_bounds__(256) void rope_kernel(float* __restrict__ Qf, float* __restrict__ Kf)
{
    int idx = blockIdx.x * 256 + threadIdx.x;      // 16*1024*32 pairs
    int i = idx & 31; int t = (idx >> 5) & 1023; int h = idx >> 15;
    // theta rounded to fp32 (as np), ang = fp32 multiply (as np), trig in double
    float theta = (float)exp((double)i * -0.28782313662425575);  // 10000^(-i/32)
    float ang = (float)t * theta;
    double sd, cd;
    sincos((double)ang, &sd, &cd);
    float c = (float)cd, s = (float)sd;
    size_t base = ((size_t)h << 16) + ((size_t)t << 6) + (size_t)(2 * i);
    float a = Qf[base], b = Qf[base + 1];
    Qf[base]     = a * c - b * s;
    Qf[base + 1] = b * c + a * s;
    a = Kf[base]; b = Kf[base + 1];
    Kf[base]     = a * c - b * s;
    Kf[base + 1] = b * c + a * s;
}

// ================================================================ Attention (two-pass, fp32, -> hi/lo A)
__global__ __launch_bounds__(128) void attn_kernel(
    const float* __restrict__ Qf, const float* __restrict__ Kf, const float* __restrict__ Vf,
    u16* __restrict__ Ah, u16* __restrict__ Al)
{
    __shared__ float Ks[128][65];
    __shared__ float sc[1024];
    __shared__ float qs[64];
    __shared__ float rb[2];
    __shared__ float red[128];

    const int t = blockIdx.x, h = blockIdx.y;
    const int tid = threadIdx.x;
    const int lane = tid & 63, wv = tid >> 6;
    const int nS = t + 1;
    const size_t hb = (size_t)h * (TSEQ * DH);

    if (tid < 64) qs[tid] = Qf[hb + (size_t)t * DH + tid];
    __syncthreads();

    for (int s0 = 0; s0 < nS; s0 += 128) {
        __syncthreads();
#pragma unroll
        for (int it = 0; it < 16; it++) {
            int fi = it * 128 + tid;
            int r = fi >> 4, c4 = (fi & 15) * 4;
            int s = s0 + r;
            if (s < TSEQ) {
                fx4 vv = *(const fx4*)(Kf + hb + (size_t)s * DH + c4);
                Ks[r][c4] = vv[0]; Ks[r][c4 + 1] = vv[1]; Ks[r][c4 + 2] = vv[2]; Ks[r][c4 + 3] = vv[3];
            }
        }
        __syncthreads();
        int s = s0 + tid;
        if (s < nS) {
            float dot = 0.f;
#pragma unroll
            for (int d = 0; d < 64; d++) dot += qs[d] * Ks[tid][d];
            sc[s] = dot * 0.125f;
        }
    }
    __syncthreads();
    float m = -3.0e38f;
    for (int s = tid; s < nS; s += 128) m = fmaxf(m, sc[s]);
#pragma unroll
    for (int off = 32; off; off >>= 1) m = fmaxf(m, __shfl_down(m, off));
    if (lane == 0) rb[wv] = m;
    __syncthreads();
    m = fmaxf(rb[0], rb[1]);
    __syncthreads();
    float l = 0.f;
    for (int s = tid; s < nS; s += 128) { float p = expf(sc[s] - m); sc[s] = p; l += p; }
#pragma unroll
    for (int off = 32; off; off >>= 1) l += __shfl_down(l, off);
    if (lane == 0) rb[wv] = l;
    __syncthreads();
    float rl = 1.0f / (rb[0] + rb[1]);

    float acc = 0.f;
    const int e = tid & 63, ch = tid >> 6;
    for (int s0 = 0; s0 < nS; s0 += 128) {
        __syncthreads();
#pragma unroll
        for (int it = 0; it < 16; it++) {
            int fi = it * 128 + tid;
            int r = fi >> 4, c4 = (fi & 15) * 4;
            int s = s0 + r;
            if (s < TSEQ) {
                fx4 vv = *(const fx4*)(Vf + hb + (size_t)s * DH + c4);
                Ks[r][c4] = vv[0]; Ks[r][c4 + 1] = vv[1]; Ks[r][c4 + 2] = vv[2]; Ks[r][c4 + 3] = vv[3];
            }
        }
        __syncthreads();
        int lim = nS - s0; if (lim > 128) lim = 128;
        int hi = ch * 64 + 64; if (hi > lim) hi = lim;
        for (int si = ch * 64; si < hi; si++) acc += sc[s0 + si] * Ks[si][e];
    }
    red[tid] = acc;
    __syncthreads();
    if (tid < 64) {
        float o = (red[tid] + red[tid + 64]) * rl;
        u16 hh = f2bf(o);
        size_t oi = (size_t)t * DMOD + h * DH + tid;
        Ah[oi] = hh;
        Al[oi] = f2bf(o - bf2f(hh));
    }
}

// ================================================================ Output projection + residual (hi/lo)
__global__ __launch_bounds__(256) void proj_kernel(
    const u16* __restrict__ Ah, const u16* __restrict__ Al, const float* __restrict__ Wp,
    const float* __restrict__ emb, const float* __restrict__ bproj,
    float* __restrict__ emb2)
{
    __shared__ u16 AsH[64 * LDA_S], AsL[64 * LDA_S], BsH[64 * LDA_S], BsL[64 * LDA_S];
    const int tid = threadIdx.x;
    const int m0 = blockIdx.x * 64, n0 = blockIdx.y * 64;
    const size_t aoff = (size_t)(m0 + (tid >> 2)) * DMOD + (tid & 3) * 8;
    size_t boff = (size_t)((tid >> 6) * 8) * DMOD + n0 + (tid & 63);
    fx4 acc[4] = {};
    gemm64_hilo(acc, Ah + aoff, Al + aoff, Wp, boff, DMOD, DMOD, AsH, AsL, BsH, BsL, tid);
    const int wave = tid >> 6, lane = tid & 63, quad = lane >> 4, l16 = lane & 15;
#pragma unroll
    for (int s = 0; s < 4; s++)
#pragma unroll
        for (int r = 0; r < 4; r++) {
            int row = m0 + wave * 16 + quad * 4 + r;
            int gcol = n0 + s * 16 + l16;
            size_t i = (size_t)row * DMOD + gcol;
            emb2[i] = acc[s][r] + emb[i] + bproj[gcol];
        }
}

// ================================================================ Router + top-2 dispatch (fp32)
__global__ __launch_bounds__(64) void router_kernel(
    const float* __restrict__ y32, const float* __restrict__ Wr, const float* __restrict__ br,
    float* __restrict__ w, int* __restrict__ cnt, int* __restrict__ list,
    float* __restrict__ gate)
{
    const int t = blockIdx.x, lane = threadIdx.x;
    float acc[8] = {0, 0, 0, 0, 0, 0, 0, 0};
    for (int d = lane; d < DMOD; d += 64) {
        float yv = y32[(size_t)t * DMOD + d];
#pragma unroll
        for (int e = 0; e < 8; e++) acc[e] += yv * Wr[(size_t)d * 8 + e];
    }
#pragma unroll
    for (int e = 0; e < 8; e++)
        for (int off = 32; off; off >>= 1) acc[e] += __shfl_down(acc[e], off);
    if (lane == 0) {
        float we[8]; float mx = -3e38f;
#pragma unroll
        for (int e = 0; e < 8; e++) { we[e] = acc[e] + br[e]; mx = fmaxf(mx, we[e]); }
        float sum = 0.f;
#pragma unroll
        for (int e = 0; e < 8; e++) { we[e] = expf(we[e] - mx); sum += we[e]; }
        float rs = 1.f / sum;
#pragma unroll
        for (int e = 0; e < 8; e++) { we[e] *= rs; w[t * 8 + e] = we[e]; }
        int e0 = 0;
#pragma unroll
        for (int e = 1; e < 8; e++) if (we[e] > we[e0]) e0 = e;
        int e1 = -1;
#pragma unroll
        for (int e = 0; e < 8; e++) if (e != e0 && (e1 < 0 || we[e] > we[e1])) e1 = e;
        float nrm = 1.f / (we[e0] + we[e1]);
        int s0 = atomicAdd(&cnt[e0], 1); list[e0 * 1024 + s0] = t; gate[e0 * 1024 + s0] = we[e0] * nrm;
        int s1 = atomicAdd(&cnt[e1], 1); list[e1 * 1024 + s1] = t; gate[e1 * 1024 + s1] = we[e1] * nrm;
    }
}

// ================================================================ MoE layer 1 (gathered)
__global__ __launch_bounds__(256) void moe1_kernel(
    const u16* __restrict__ y, const float* __restrict__ W1, const float* __restrict__ b1,
    const int* __restrict__ cnt, const int* __restrict__ list, u16* __restrict__ hbuf)
{
    const int e = blockIdx.z;
    const int count = cnt[e];
    const int m0 = blockIdx.x * 64;
    if (m0 >= count) return;
    const int n0 = blockIdx.y * 64;
    __shared__ u16 As[64 * LDA_S], Bs[64 * LDA_S];
    __shared__ int toks[64];
    const int tid = threadIdx.x;
    if (tid < 64) { int idx = m0 + tid; toks[tid] = (idx < count) ? list[e * 1024 + idx] : -1; }
    __syncthreads();
    int tk = toks[tid >> 2];
    const u16* aptr = (tk >= 0) ? (y + (size_t)tk * DMOD + (tid & 3) * 8) : (const u16*)nullptr;
    size_t boff = (size_t)e * DMOD * DFF + (size_t)((tid >> 6) * 8) * DFF + n0 + (tid & 63);
    fx4 acc[4] = {};
    gemm64_loop(acc, aptr, W1, boff, DFF, DMOD, As, Bs, tid);
    const int wave = tid >> 6, lane = tid & 63, quad = lane >> 4, l16 = lane & 15;
#pragma unroll
    for (int s = 0; s < 4; s++)
#pragma unroll
        for (int r = 0; r < 4; r++) {
            int slot = m0 + wave * 16 + quad * 4 + r;
            if (slot < count) {
                int gcol = n0 + s * 16 + l16;
                float v = acc[s][r] + b1[e * DFF + gcol];
                hbuf[((size_t)e * 1024 + slot) * DFF + gcol] = f2bf(fmaxf(v, 0.f));
            }
        }
}

// ================================================================ MoE layer 2 + gated scatter
__global__ __launch_bounds__(256) void moe2_kernel(
    const u16* __restrict__ hbuf, const float* __restrict__ W2, const float* __restrict__ b2,
    const int* __restrict__ cnt, const int* __restrict__ list, const float* __restrict__ gate,
    float* __restrict__ moe)
{
    const int e = blockIdx.z;
    const int count = cnt[e];
    const int m0 = blockIdx.x * 64;
    if (m0 >= count) return;
    const int n0 = blockIdx.y * 64;
    __shared__ u16 As[64 * LDA_S], Bs[64 * LDA_S];
    const int tid = threadIdx.x;
    const u16* aptr = hbuf + ((size_t)e * 1024 + m0 + (tid >> 2)) * DFF + (tid & 3) * 8;
    size_t boff = (size_t)e * DFF * DMOD + (size_t)((tid >> 6) * 8) * DMOD + n0 + (tid & 63);
    fx4 acc[4] = {};
    gemm64_loop(acc, aptr, W2, boff, DMOD, DFF, As, Bs, tid);
    const int wave = tid >> 6, lane = tid & 63, quad = lane >> 4, l16 = lane & 15;
#pragma unroll
    for (int s = 0; s < 4; s++)
#pragma unroll
        for (int r = 0; r < 4; r++) {
            int slot = m0 + wave * 16 + quad * 4 + r;
            if (slot < count) {
                int tkn = list[e * 1024 + slot];
                float g = gate[e * 1024 + slot];
                int gcol = n0 + s * 16 + l16;
                float v = acc[s][r] + b2[e * DMOD + gcol];
                atomicAdd(&moe[(size_t)tkn * DMOD + gcol], g * v);
            }
        }
}

// ================================================================ final combine + aux
__global__ __launch_bounds__(256) void combine_kernel(
    const float* __restrict__ emb2, const float* __restrict__ moe, float* __restrict__ outp)
{
    int i4 = blockIdx.x * 256 + threadIdx.x;
    fx4 a = *(const fx4*)(emb2 + (size_t)i4 * 4);
    fx4 b = *(const fx4*)(moe + (size_t)i4 * 4);
    fx4 o;
#pragma unroll
    for (int j = 0; j < 4; j++) o[j] = a[j] + b[j];
    *(fx4*)(outp + (size_t)i4 * 4) = o;
}

__global__ __launch_bounds__(64) void aux_kernel(const float* __restrict__ w, float* __restrict__ outp)
{
    int lane = threadIdx.x;
    int e = lane & 7, ch = lane >> 3;
    float s = 0.f;
    for (int t = ch * 128; t < ch * 128 + 128; t++) s += w[t * 8 + e];
    for (int off = 32; off >= 8; off >>= 1) s += __shfl_down(s, off);
    float d = s * (1.f / 1024.f) - 0.125f;
    float q = d * d;
    for (int off = 4; off; off >>= 1) q += __shfl_down(q, off);
    if (lane == 0) outp[(size_t)TSEQ * DMOD] = q * (1.f / 8.f);
}

// ================================================================ launch
extern "C" void kernel_launch(void* const* d_in, const int* in_sizes, int n_in,
                              void* d_out, int out_size, void* d_ws, size_t ws_size,
                              hipStream_t stream) {
    const float* emb   = (const float*)d_in[0];
    const float* g1    = (const float*)d_in[1];
    const float* be1   = (const float*)d_in[2];
    const float* WQ    = (const float*)d_in[3];
    const float* WK    = (const float*)d_in[4];
    const float* WV    = (const float*)d_in[5];
    const float* Wp    = (const float*)d_in[6];
    const float* bproj = (const float*)d_in[7];
    const float* g2    = (const float*)d_in[8];
    const float* be2   = (const float*)d_in[9];
    const float* Wr    = (const float*)d_in[10];
    const float* br    = (const float*)d_in[11];
    const float* W1    = (const float*)d_in[12];
    const float* b1e   = (const float*)d_in[13];
    const float* W2    = (const float*)d_in[14];
    const float* b2e   = (const float*)d_in[15];
    float* out = (float*)d_out;
    char* ws = (char*)d_ws;

    u16*   hbuf = (u16*)  (ws + H_OFF);
    u16*   xh   = (u16*)  (ws + XH_OFF);
    u16*   xl   = (u16*)  (ws + XL_OFF);
    float* Qf   = (float*)(ws + Q_OFF);
    float* Kf   = (float*)(ws + K_OFF);
    float* Vf   = (float*)(ws + V_OFF);
    u16*   Ah   = (u16*)  (ws + AH_OFF);
    u16*   Al   = (u16*)  (ws + AL_OFF);
    float* emb2 = (float*)(ws + E2_OFF);
    float* y32  = (float*)(ws + Y32_OFF);
    u16*   ybf  = (u16*)  (ws + YBF_OFF);
    float* moe  = (float*)(ws + MOE_OFF);
    float* wbuf = (float*)(ws + W_OFF);
    int*   cnt  = (int*)  (ws + CNT_OFF);
    int*   list = (int*)  (ws + LIST_OFF);
    float* gate = (float*)(ws + GATE_OFF);

    hipMemsetAsync(moe, 0, (size_t)TSEQ * DMOD * sizeof(float), stream);
    hipMemsetAsync(cnt, 0, 8 * sizeof(int), stream);

    ln1_kernel<<<TSEQ, 256, 0, stream>>>(emb, g1, be1, xh, xl);
    qkv_kernel<<<dim3(16, 16, 3), 256, 0, stream>>>(xh, xl, WQ, WK, WV, Qf, Kf, Vf);
    rope_kernel<<<2048, 256, 0, stream>>>(Qf, Kf);
    attn_kernel<<<dim3(TSEQ, NH), 128, 0, stream>>>(Qf, Kf, Vf, Ah, Al);
    proj_kernel<<<dim3(16, 16), 256, 0, stream>>>(Ah, Al, Wp, emb, bproj, emb2);
    ln2_kernel<<<TSEQ, 256, 0, stream>>>(emb2, g2, be2, y32, ybf);
    router_kernel<<<TSEQ, 64, 0, stream>>>(y32, Wr, br, wbuf, cnt, list, gate);
    moe1_kernel<<<dim3(16, 64, 8), 256, 0, stream>>>(ybf, W1, b1e, cnt, list, hbuf);
    moe2_kernel<<<dim3(16, 16, 8), 256, 0, stream>>>(hbuf, W2, b2e, cnt, list, gate, moe);
    combine_kernel<<<1024, 256, 0, stream>>>(emb2, moe, out);
    aux_kernel<<<1, 64, 0, stream>>>(wbuf, out);
}

// Round 4
// 912.122 us; speedup vs baseline: 1.7265x; 1.7265x over previous
//
#include <hip/hip_runtime.h>

// ---------------------------------------------------------------- types
typedef unsigned short u16;
typedef unsigned int u32;
typedef __attribute__((ext_vector_type(8))) unsigned short ushortx8;
typedef __attribute__((ext_vector_type(4))) unsigned short ushortx4;
typedef __attribute__((ext_vector_type(8))) short short8;
typedef __attribute__((ext_vector_type(4))) float fx4;

__device__ __forceinline__ float bf2f(u16 v) {
    union { u32 u; float f; } x; x.u = ((u32)v) << 16; return x.f;
}
__device__ __forceinline__ u16 f2bf(float f) {
    union { float f; u32 u; } x; x.f = f;
    u32 r = x.u + 0x7fffu + ((x.u >> 16) & 1u);
    return (u16)(r >> 16);
}

// ---------------------------------------------------------------- sizes
#define TSEQ 1024
#define DMOD 1024
#define NH   16
#define DH   64
#define NE   8
#define DFF  4096

// ---------------------------------------------------------------- ws layout (bytes)
// Phase 1 (attention) buffers live in [0, 64MB); hbuf (moe phase) overlays them.
#define H_OFF    ((size_t)0)                        // u16 8x1024x4096 (64MB) moe1->moe2
#define XH_OFF   ((size_t)0)                        // u16 1M LN1 hi
#define XL_OFF   ((size_t)2  << 20)                 // u16 1M LN1 lo
#define QF_OFF   ((size_t)4  << 20)                 // f32 1M
#define KF_OFF   ((size_t)8  << 20)                 // f32 1M
#define VF_OFF   ((size_t)12 << 20)                 // f32 1M
#define QH_OFF   ((size_t)16 << 20)                 // u16 1M (roped, hi)
#define QL_OFF   ((size_t)18 << 20)
#define KH_OFF   ((size_t)20 << 20)
#define KL_OFF   ((size_t)22 << 20)
#define VH_OFF   ((size_t)24 << 20)
#define VL_OFF   ((size_t)26 << 20)
#define AH_OFF   ((size_t)28 << 20)                 // u16 1M attn out hi
#define AL_OFF   ((size_t)30 << 20)                 // u16 1M attn out lo
// persistent phase-2 buffers >= 64MB
#define E2_OFF   ((size_t)64 << 20)                 // f32 1M emb2
#define Y32_OFF  ((size_t)68 << 20)                 // f32 1M LN2 fp32
#define YBF_OFF  ((size_t)72 << 20)                 // u16 1M LN2 bf16
#define MOE_OFF  ((size_t)74 << 20)                 // f32 1M moe accum
#define W_OFF    ((size_t)78 << 20)                 // f32 1024x8
#define CNT_OFF  (((size_t)78 << 20) + 64*1024)
#define LIST_OFF (((size_t)78 << 20) + 128*1024)
#define GATE_OFF (((size_t)78 << 20) + 192*1024)

// ================================================================ LayerNorm 1 -> hi/lo bf16
__global__ __launch_bounds__(256) void ln1_kernel(
    const float* __restrict__ in, const float* __restrict__ gamma,
    const float* __restrict__ beta, u16* __restrict__ xh, u16* __restrict__ xl)
{
    __shared__ float rs[4], rs2[4];
    const int row = blockIdx.x, tid = threadIdx.x;
    fx4 v = *(const fx4*)(in + (size_t)row * DMOD + tid * 4);
    float s = 0.f, s2 = 0.f;
#pragma unroll
    for (int j = 0; j < 4; j++) { s += v[j]; s2 += v[j] * v[j]; }
#pragma unroll
    for (int off = 32; off; off >>= 1) { s += __shfl_down(s, off); s2 += __shfl_down(s2, off); }
    if ((tid & 63) == 0) { rs[tid >> 6] = s; rs2[tid >> 6] = s2; }
    __syncthreads();
    float S = rs[0] + rs[1] + rs[2] + rs[3];
    float S2 = rs2[0] + rs2[1] + rs2[2] + rs2[3];
    float mean = S * (1.f / DMOD);
    float var  = S2 * (1.f / DMOD) - mean * mean;
    float inv = rsqrtf(var + 1e-6f);
    fx4 gv = *(const fx4*)(gamma + tid * 4);
    fx4 bv = *(const fx4*)(beta + tid * 4);
    ushortx4 oh, ol;
#pragma unroll
    for (int j = 0; j < 4; j++) {
        float r = (v[j] - mean) * inv * gv[j] + bv[j];
        u16 h = f2bf(r);
        oh[j] = h; ol[j] = f2bf(r - bf2f(h));
    }
    *(ushortx4*)(xh + (size_t)row * DMOD + tid * 4) = oh;
    *(ushortx4*)(xl + (size_t)row * DMOD + tid * 4) = ol;
}

// LN2: f32 in -> f32 (router) + bf16 (MoE GEMM A)
__global__ __launch_bounds__(256) void ln2_kernel(
    const float* __restrict__ in, const float* __restrict__ gamma,
    const float* __restrict__ beta, float* __restrict__ y32, u16* __restrict__ ybf)
{
    __shared__ float rs[4], rs2[4];
    const int row = blockIdx.x, tid = threadIdx.x;
    fx4 v = *(const fx4*)(in + (size_t)row * DMOD + tid * 4);
    float s = 0.f, s2 = 0.f;
#pragma unroll
    for (int j = 0; j < 4; j++) { s += v[j]; s2 += v[j] * v[j]; }
#pragma unroll
    for (int off = 32; off; off >>= 1) { s += __shfl_down(s, off); s2 += __shfl_down(s2, off); }
    if ((tid & 63) == 0) { rs[tid >> 6] = s; rs2[tid >> 6] = s2; }
    __syncthreads();
    float S = rs[0] + rs[1] + rs[2] + rs[3];
    float S2 = rs2[0] + rs2[1] + rs2[2] + rs2[3];
    float mean = S * (1.f / DMOD);
    float var  = S2 * (1.f / DMOD) - mean * mean;
    float inv = rsqrtf(var + 1e-6f);
    fx4 gv = *(const fx4*)(gamma + tid * 4);
    fx4 bv = *(const fx4*)(beta + tid * 4);
    fx4 o32; ushortx4 o;
#pragma unroll
    for (int j = 0; j < 4; j++) {
        float r = (v[j] - mean) * inv * gv[j] + bv[j];
        o32[j] = r; o[j] = f2bf(r);
    }
    *(fx4*)(y32 + (size_t)row * DMOD + tid * 4) = o32;
    *(ushortx4*)(ybf + (size_t)row * DMOD + tid * 4) = o;
}

// ================================================================ GEMM mainloops (64x64 tile, 4 waves)
#define LDA_S 40

__device__ __forceinline__ void gemm64_loop(
    fx4 acc[4], const u16* aptr, const float* __restrict__ B, size_t boff,
    int ldb, int K, u16* As, u16* Bs, int tid)
{
    const int wave = tid >> 6, lane = tid & 63, quad = lane >> 4, l16 = lane & 15;
    const int ar = tid >> 2, ak = (tid & 3) * 8;
    for (int k0 = 0; k0 < K; k0 += 32) {
        __syncthreads();
        ushortx8 av;
#pragma unroll
        for (int j = 0; j < 8; j++) av[j] = 0;
        if (aptr) av = *(const ushortx8*)(aptr + k0);
        *(ushortx8*)(&As[ar * LDA_S + ak]) = av;
        ushortx8 bv;
#pragma unroll
        for (int j = 0; j < 8; j++) bv[j] = f2bf(B[boff + (size_t)(k0 + j) * ldb]);
        *(ushortx8*)(&Bs[(tid & 63) * LDA_S + (tid >> 6) * 8]) = bv;
        __syncthreads();
        short8 af = *(const short8*)(&As[(wave * 16 + l16) * LDA_S + quad * 8]);
#pragma unroll
        for (int s = 0; s < 4; s++) {
            short8 bf_ = *(const short8*)(&Bs[(s * 16 + l16) * LDA_S + quad * 8]);
            acc[s] = __builtin_amdgcn_mfma_f32_16x16x32_bf16(af, bf_, acc[s], 0, 0, 0);
        }
    }
}

// hi/lo (Markidis): acc += Ah*Bl + Al*Bh + Ah*Bh
__device__ __forceinline__ void gemm64_hilo(
    fx4 acc[4], const u16* ahi, const u16* alo, const float* __restrict__ B, size_t boff,
    int ldb, int K, u16* AsH, u16* AsL, u16* BsH, u16* BsL, int tid)
{
    const int wave = tid >> 6, lane = tid & 63, quad = lane >> 4, l16 = lane & 15;
    const int ar = tid >> 2, ak = (tid & 3) * 8;
    for (int k0 = 0; k0 < K; k0 += 32) {
        __syncthreads();
        *(ushortx8*)(&AsH[ar * LDA_S + ak]) = *(const ushortx8*)(ahi + k0);
        *(ushortx8*)(&AsL[ar * LDA_S + ak]) = *(const ushortx8*)(alo + k0);
        ushortx8 bh, bl;
#pragma unroll
        for (int j = 0; j < 8; j++) {
            float w = B[boff + (size_t)(k0 + j) * ldb];
            u16 hh = f2bf(w);
            bh[j] = hh; bl[j] = f2bf(w - bf2f(hh));
        }
        *(ushortx8*)(&BsH[(tid & 63) * LDA_S + (tid >> 6) * 8]) = bh;
        *(ushortx8*)(&BsL[(tid & 63) * LDA_S + (tid >> 6) * 8]) = bl;
        __syncthreads();
        short8 ah = *(const short8*)(&AsH[(wave * 16 + l16) * LDA_S + quad * 8]);
        short8 al = *(const short8*)(&AsL[(wave * 16 + l16) * LDA_S + quad * 8]);
#pragma unroll
        for (int s = 0; s < 4; s++) {
            short8 bhf = *(const short8*)(&BsH[(s * 16 + l16) * LDA_S + quad * 8]);
            short8 blf = *(const short8*)(&BsL[(s * 16 + l16) * LDA_S + quad * 8]);
            acc[s] = __builtin_amdgcn_mfma_f32_16x16x32_bf16(ah, blf, acc[s], 0, 0, 0);
            acc[s] = __builtin_amdgcn_mfma_f32_16x16x32_bf16(al, bhf, acc[s], 0, 0, 0);
            acc[s] = __builtin_amdgcn_mfma_f32_16x16x32_bf16(ah, bhf, acc[s], 0, 0, 0);
        }
    }
}

// ================================================================ QKV projection (hi/lo)
__global__ __launch_bounds__(256) void qkv_kernel(
    const u16* __restrict__ xh, const u16* __restrict__ xl,
    const float* __restrict__ WQ, const float* __restrict__ WK, const float* __restrict__ WV,
    float* __restrict__ Qf, float* __restrict__ Kf, float* __restrict__ Vf)
{
    __shared__ u16 AsH[64 * LDA_S], AsL[64 * LDA_S], BsH[64 * LDA_S], BsL[64 * LDA_S];
    const int tid = threadIdx.x;
    const int mt = blockIdx.x, h = blockIdx.y, z = blockIdx.z;
    const float* W = (z == 0) ? WQ : (z == 1) ? WK : WV;
    float* Out = (z == 0) ? Qf : (z == 1) ? Kf : Vf;
    const int m0 = mt * 64;
    const size_t aoff = (size_t)(m0 + (tid >> 2)) * DMOD + (tid & 3) * 8;
    size_t boff = (size_t)h * (DMOD * DH) + (size_t)((tid >> 6) * 8) * DH + (tid & 63);
    fx4 acc[4] = {};
    gemm64_hilo(acc, xh + aoff, xl + aoff, W, boff, DH, DMOD, AsH, AsL, BsH, BsL, tid);
    const int wave = tid >> 6, lane = tid & 63, quad = lane >> 4, l16 = lane & 15;
    float* ob = Out + (size_t)h * (TSEQ * DH);
#pragma unroll
    for (int s = 0; s < 4; s++)
#pragma unroll
        for (int r = 0; r < 4; r++) {
            int row = m0 + wave * 16 + quad * 4 + r;
            int col = s * 16 + l16;
            ob[(size_t)row * DH + col] = acc[s][r];
        }
}

// ================================================================ RoPE + bf16 hi/lo convert (Q,K roped; V split only)
__global__ __launch_bounds__(256) void rope_cvt_kernel(
    const float* __restrict__ Qf, const float* __restrict__ Kf, const float* __restrict__ Vf,
    u16* __restrict__ Qh, u16* __restrict__ Ql, u16* __restrict__ Kh, u16* __restrict__ Kl,
    u16* __restrict__ Vh, u16* __restrict__ Vl)
{
    int idx = blockIdx.x * 256 + threadIdx.x;      // 16*1024*32 pairs
    int i = idx & 31; int t = (idx >> 5) & 1023; int h = idx >> 15;
    float theta = (float)exp((double)i * -0.28782313662425575);  // 10000^(-i/32)
    float ang = (float)t * theta;
    double sd, cd;
    sincos((double)ang, &sd, &cd);
    float c = (float)cd, s = (float)sd;
    size_t base = ((size_t)h << 16) + ((size_t)t << 6) + (size_t)(2 * i);

    float a = Qf[base], b = Qf[base + 1];
    float q0 = a * c - b * s, q1 = b * c + a * s;
    u16 h0 = f2bf(q0), h1 = f2bf(q1);
    *(u32*)(Qh + base) = (u32)h0 | ((u32)h1 << 16);
    *(u32*)(Ql + base) = (u32)f2bf(q0 - bf2f(h0)) | ((u32)f2bf(q1 - bf2f(h1)) << 16);

    a = Kf[base]; b = Kf[base + 1];
    q0 = a * c - b * s; q1 = b * c + a * s;
    h0 = f2bf(q0); h1 = f2bf(q1);
    *(u32*)(Kh + base) = (u32)h0 | ((u32)h1 << 16);
    *(u32*)(Kl + base) = (u32)f2bf(q0 - bf2f(h0)) | ((u32)f2bf(q1 - bf2f(h1)) << 16);

    q0 = Vf[base]; q1 = Vf[base + 1];
    h0 = f2bf(q0); h1 = f2bf(q1);
    *(u32*)(Vh + base) = (u32)h0 | ((u32)h1 << 16);
    *(u32*)(Vl + base) = (u32)f2bf(q0 - bf2f(h0)) | ((u32)f2bf(q1 - bf2f(h1)) << 16);
}

// ================================================================ Flash attention, MFMA hi/lo
// Block: 64 q-rows x 1 head; 4 waves, each owns 16 q-rows. K/V tiles of 64.
#define LDK 72   // row stride (elems) for 64-wide bf16 LDS tiles (b128-aligned, 2-way banks)

__global__ __launch_bounds__(256) void attn_kernel(
    const u16* __restrict__ Qh_, const u16* __restrict__ Ql_,
    const u16* __restrict__ Kh_, const u16* __restrict__ Kl_,
    const u16* __restrict__ Vh_, const u16* __restrict__ Vl_,
    u16* __restrict__ Ah, u16* __restrict__ Al)
{
    __shared__ u16 Ksh[64 * LDK], Ksl[64 * LDK];
    __shared__ u16 Vsh[64 * LDK], Vsl[64 * LDK];   // transposed: [dh][key]
    __shared__ u16 Psh[64 * LDK], Psl[64 * LDK];   // [qrow][key]
    const int tid = threadIdx.x;
    const int w = tid >> 6, lane = tid & 63, quad = lane >> 4, l16 = lane & 15;
    const int t0 = blockIdx.x * 64, h = blockIdx.y;
    const size_t hb = (size_t)h * (TSEQ * DH);

    // Q fragments (A-operand): rows t0 + w*16 + l16, k = kc*32 + quad*8 + j
    short8 qh[2], ql[2];
    {
        size_t qb = hb + (size_t)(t0 + w * 16 + l16) * DH + quad * 8;
        qh[0] = *(const short8*)(Qh_ + qb);
        qh[1] = *(const short8*)(Qh_ + qb + 32);
        ql[0] = *(const short8*)(Ql_ + qb);
        ql[1] = *(const short8*)(Ql_ + qb + 32);
    }
    fx4 O[4] = {};                 // O[seg]: row quad*4+r, dh seg*16+l16
    float mrow[4] = {-3e38f, -3e38f, -3e38f, -3e38f};
    float lrow[4] = {0.f, 0.f, 0.f, 0.f};

    for (int s0 = 0; s0 <= t0; s0 += 64) {
        __syncthreads();           // prior tile fully consumed
        // stage K (hi/lo), natural layout [key][dh]
        for (int i = tid; i < 512; i += 256) {
            int r = i >> 3, c = (i & 7) * 8;
            *(ushortx8*)(&Ksh[r * LDK + c]) = *(const ushortx8*)(Kh_ + hb + (size_t)(s0 + r) * DH + c);
            *(ushortx8*)(&Ksl[r * LDK + c]) = *(const ushortx8*)(Kl_ + hb + (size_t)(s0 + r) * DH + c);
        }
        // stage V transposed [dh][key]
        for (int i = tid; i < 512; i += 256) {
            int r = i >> 3, c = (i & 7) * 8;   // key r, dh c..c+7
            ushortx8 vh = *(const ushortx8*)(Vh_ + hb + (size_t)(s0 + r) * DH + c);
            ushortx8 vl = *(const ushortx8*)(Vl_ + hb + (size_t)(s0 + r) * DH + c);
#pragma unroll
            for (int j = 0; j < 8; j++) {
                Vsh[(c + j) * LDK + r] = vh[j];
                Vsl[(c + j) * LDK + r] = vl[j];
            }
        }
        __syncthreads();

        // S = (Q K^T) hi/lo
        fx4 S[4] = {};
#pragma unroll
        for (int kc = 0; kc < 2; kc++)
#pragma unroll
            for (int s = 0; s < 4; s++) {
                short8 kh = *(const short8*)(&Ksh[(s * 16 + l16) * LDK + kc * 32 + quad * 8]);
                short8 kl = *(const short8*)(&Ksl[(s * 16 + l16) * LDK + kc * 32 + quad * 8]);
                S[s] = __builtin_amdgcn_mfma_f32_16x16x32_bf16(qh[kc], kl, S[s], 0, 0, 0);
                S[s] = __builtin_amdgcn_mfma_f32_16x16x32_bf16(ql[kc], kh, S[s], 0, 0, 0);
                S[s] = __builtin_amdgcn_mfma_f32_16x16x32_bf16(qh[kc], kh, S[s], 0, 0, 0);
            }

        const bool diag = (s0 == t0);
#pragma unroll
        for (int r = 0; r < 4; r++) {
            float pv[4]; float mx = -3e38f;
#pragma unroll
            for (int s = 0; s < 4; s++) {
                float v = S[s][r] * 0.125f;
                if (diag && (16 * s + l16 > w * 16 + quad * 4 + r)) v = -3e38f;
                pv[s] = v; mx = fmaxf(mx, v);
            }
            mx = fmaxf(mx, __shfl_xor(mx, 1));
            mx = fmaxf(mx, __shfl_xor(mx, 2));
            mx = fmaxf(mx, __shfl_xor(mx, 4));
            mx = fmaxf(mx, __shfl_xor(mx, 8));
            float mnew = fmaxf(mrow[r], mx);
            float alpha = expf(mrow[r] - mnew);
            float rsum = 0.f;
#pragma unroll
            for (int s = 0; s < 4; s++) { float p = expf(pv[s] - mnew); pv[s] = p; rsum += p; }
            rsum += __shfl_xor(rsum, 1);
            rsum += __shfl_xor(rsum, 2);
            rsum += __shfl_xor(rsum, 4);
            rsum += __shfl_xor(rsum, 8);
            lrow[r] = lrow[r] * alpha + rsum;
            mrow[r] = mnew;
#pragma unroll
            for (int seg = 0; seg < 4; seg++) O[seg][r] *= alpha;
            int prow = (w * 16 + quad * 4 + r) * LDK;
#pragma unroll
            for (int s = 0; s < 4; s++) {
                u16 ph = f2bf(pv[s]);
                Psh[prow + 16 * s + l16] = ph;
                Psl[prow + 16 * s + l16] = f2bf(pv[s] - bf2f(ph));
            }
        }
        // PV (wave reads only its own 16 P-rows -> no barrier needed; lgkmcnt by compiler)
#pragma unroll
        for (int kc = 0; kc < 2; kc++) {
            short8 ph = *(const short8*)(&Psh[(w * 16 + l16) * LDK + kc * 32 + quad * 8]);
            short8 pl = *(const short8*)(&Psl[(w * 16 + l16) * LDK + kc * 32 + quad * 8]);
#pragma unroll
            for (int seg = 0; seg < 4; seg++) {
                short8 vh = *(const short8*)(&Vsh[(seg * 16 + l16) * LDK + kc * 32 + quad * 8]);
                short8 vl = *(const short8*)(&Vsl[(seg * 16 + l16) * LDK + kc * 32 + quad * 8]);
                O[seg] = __builtin_amdgcn_mfma_f32_16x16x32_bf16(ph, vl, O[seg], 0, 0, 0);
                O[seg] = __builtin_amdgcn_mfma_f32_16x16x32_bf16(pl, vh, O[seg], 0, 0, 0);
                O[seg] = __builtin_amdgcn_mfma_f32_16x16x32_bf16(ph, vh, O[seg], 0, 0, 0);
            }
        }
    }
    // epilogue: normalize, hi/lo split, write [t][h*64+dh]
#pragma unroll
    for (int seg = 0; seg < 4; seg++)
#pragma unroll
        for (int r = 0; r < 4; r++) {
            int trow = t0 + w * 16 + quad * 4 + r;
            float o = O[seg][r] / lrow[r];
            u16 hh = f2bf(o);
            size_t oi = (size_t)trow * DMOD + h * 64 + seg * 16 + l16;
            Ah[oi] = hh;
            Al[oi] = f2bf(o - bf2f(hh));
        }
}

// ================================================================ Output projection + residual (hi/lo)
__global__ __launch_bounds__(256) void proj_kernel(
    const u16* __restrict__ Ah, const u16* __restrict__ Al, const float* __restrict__ Wp,
    const float* __restrict__ emb, const float* __restrict__ bproj,
    float* __restrict__ emb2)
{
    __shared__ u16 AsH[64 * LDA_S], AsL[64 * LDA_S], BsH[64 * LDA_S], BsL[64 * LDA_S];
    const int tid = threadIdx.x;
    const int m0 = blockIdx.x * 64, n0 = blockIdx.y * 64;
    const size_t aoff = (size_t)(m0 + (tid >> 2)) * DMOD + (tid & 3) * 8;
    size_t boff = (size_t)((tid >> 6) * 8) * DMOD + n0 + (tid & 63);
    fx4 acc[4] = {};
    gemm64_hilo(acc, Ah + aoff, Al + aoff, Wp, boff, DMOD, DMOD, AsH, AsL, BsH, BsL, tid);
    const int wave = tid >> 6, lane = tid & 63, quad = lane >> 4, l16 = lane & 15;
#pragma unroll
    for (int s = 0; s < 4; s++)
#pragma unroll
        for (int r = 0; r < 4; r++) {
            int row = m0 + wave * 16 + quad * 4 + r;
            int gcol = n0 + s * 16 + l16;
            size_t i = (size_t)row * DMOD + gcol;
            emb2[i] = acc[s][r] + emb[i] + bproj[gcol];
        }
}

// ================================================================ Router + top-2 dispatch (fp32)
__global__ __launch_bounds__(64) void router_kernel(
    const float* __restrict__ y32, const float* __restrict__ Wr, const float* __restrict__ br,
    float* __restrict__ w, int* __restrict__ cnt, int* __restrict__ list,
    float* __restrict__ gate)
{
    const int t = blockIdx.x, lane = threadIdx.x;
    float acc[8] = {0, 0, 0, 0, 0, 0, 0, 0};
    for (int d = lane; d < DMOD; d += 64) {
        float yv = y32[(size_t)t * DMOD + d];
#pragma unroll
        for (int e = 0; e < 8; e++) acc[e] += yv * Wr[(size_t)d * 8 + e];
    }
#pragma unroll
    for (int e = 0; e < 8; e++)
        for (int off = 32; off; off >>= 1) acc[e] += __shfl_down(acc[e], off);
    if (lane == 0) {
        float we[8]; float mx = -3e38f;
#pragma unroll
        for (int e = 0; e < 8; e++) { we[e] = acc[e] + br[e]; mx = fmaxf(mx, we[e]); }
        float sum = 0.f;
#pragma unroll
        for (int e = 0; e < 8; e++) { we[e] = expf(we[e] - mx); sum += we[e]; }
        float rs = 1.f / sum;
#pragma unroll
        for (int e = 0; e < 8; e++) { we[e] *= rs; w[t * 8 + e] = we[e]; }
        int e0 = 0;
#pragma unroll
        for (int e = 1; e < 8; e++) if (we[e] > we[e0]) e0 = e;
        int e1 = -1;
#pragma unroll
        for (int e = 0; e < 8; e++) if (e != e0 && (e1 < 0 || we[e] > we[e1])) e1 = e;
        float nrm = 1.f / (we[e0] + we[e1]);
        int s0 = atomicAdd(&cnt[e0], 1); list[e0 * 1024 + s0] = t; gate[e0 * 1024 + s0] = we[e0] * nrm;
        int s1 = atomicAdd(&cnt[e1], 1); list[e1 * 1024 + s1] = t; gate[e1 * 1024 + s1] = we[e1] * nrm;
    }
}

// ================================================================ MoE layer 1: block owns (n-panel, expert), loops m-tiles
__global__ __launch_bounds__(256) void moe1_kernel(
    const u16* __restrict__ y, const float* __restrict__ W1, const float* __restrict__ b1,
    const int* __restrict__ cnt, const int* __restrict__ list, u16* __restrict__ hbuf)
{
    const int e = blockIdx.y;
    const int count = cnt[e];
    const int n0 = blockIdx.x * 64;
    __shared__ u16 As[64 * LDA_S], Bs[64 * LDA_S];
    __shared__ int toks[64];
    const int tid = threadIdx.x;
    const int wave = tid >> 6, lane = tid & 63, quad = lane >> 4, l16 = lane & 15;
    const size_t boff = (size_t)e * DMOD * DFF + (size_t)((tid >> 6) * 8) * DFF + n0 + (tid & 63);
    for (int m0 = 0; m0 < count; m0 += 64) {
        __syncthreads();
        if (tid < 64) { int idx = m0 + tid; toks[tid] = (idx < count) ? list[e * 1024 + idx] : -1; }
        __syncthreads();
        int tk = toks[tid >> 2];
        const u16* aptr = (tk >= 0) ? (y + (size_t)tk * DMOD + (tid & 3) * 8) : (const u16*)nullptr;
        fx4 acc[4] = {};
        gemm64_loop(acc, aptr, W1, boff, DFF, DMOD, As, Bs, tid);
#pragma unroll
        for (int s = 0; s < 4; s++)
#pragma unroll
            for (int r = 0; r < 4; r++) {
                int slot = m0 + wave * 16 + quad * 4 + r;
                if (slot < count) {
                    int gcol = n0 + s * 16 + l16;
                    float v = acc[s][r] + b1[e * DFF + gcol];
                    hbuf[((size_t)e * 1024 + slot) * DFF + gcol] = f2bf(fmaxf(v, 0.f));
                }
            }
    }
}

// ================================================================ MoE layer 2: (n-panel, m-group, expert), loops m-tiles
__global__ __launch_bounds__(256) void moe2_kernel(
    const u16* __restrict__ hbuf, const float* __restrict__ W2, const float* __restrict__ b2,
    const int* __restrict__ cnt, const int* __restrict__ list, const float* __restrict__ gate,
    float* __restrict__ moe)
{
    const int e = blockIdx.z;
    const int count = cnt[e];
    const int n0 = blockIdx.x * 64;
    const int mg = blockIdx.y;                     // 0,1
    __shared__ u16 As[64 * LDA_S], Bs[64 * LDA_S];
    const int tid = threadIdx.x;
    const int wave = tid >> 6, lane = tid & 63, quad = lane >> 4, l16 = lane & 15;
    const size_t boff = (size_t)e * DFF * DMOD + (size_t)((tid >> 6) * 8) * DMOD + n0 + (tid & 63);
    for (int m0 = mg * 64; m0 < count; m0 += 128) {
        const u16* aptr = hbuf + ((size_t)e * 1024 + m0 + (tid >> 2)) * DFF + (tid & 3) * 8;
        fx4 acc[4] = {};
        gemm64_loop(acc, aptr, W2, boff, DMOD, DFF, As, Bs, tid);
#pragma unroll
        for (int s = 0; s < 4; s++)
#pragma unroll
            for (int r = 0; r < 4; r++) {
                int slot = m0 + wave * 16 + quad * 4 + r;
                if (slot < count) {
                    int tkn = list[e * 1024 + slot];
                    float g = gate[e * 1024 + slot];
                    int gcol = n0 + s * 16 + l16;
                    float v = acc[s][r] + b2[e * DMOD + gcol];
                    atomicAdd(&moe[(size_t)tkn * DMOD + gcol], g * v);
                }
            }
    }
}

// ================================================================ final combine + aux
__global__ __launch_bounds__(256) void combine_kernel(
    const float* __restrict__ emb2, const float* __restrict__ moe, float* __restrict__ outp)
{
    int i4 = blockIdx.x * 256 + threadIdx.x;
    fx4 a = *(const fx4*)(emb2 + (size_t)i4 * 4);
    fx4 b = *(const fx4*)(moe + (size_t)i4 * 4);
    fx4 o;
#pragma unroll
    for (int j = 0; j < 4; j++) o[j] = a[j] + b[j];
    *(fx4*)(outp + (size_t)i4 * 4) = o;
}

__global__ __launch_bounds__(64) void aux_kernel(const float* __restrict__ w, float* __restrict__ outp)
{
    int lane = threadIdx.x;
    int e = lane & 7, ch = lane >> 3;
    float s = 0.f;
    for (int t = ch * 128; t < ch * 128 + 128; t++) s += w[t * 8 + e];
    for (int off = 32; off >= 8; off >>= 1) s += __shfl_down(s, off);
    float d = s * (1.f / 1024.f) - 0.125f;
    float q = d * d;
    for (int off = 4; off; off >>= 1) q += __shfl_down(q, off);
    if (lane == 0) outp[(size_t)TSEQ * DMOD] = q * (1.f / 8.f);
}

// ================================================================ launch
extern "C" void kernel_launch(void* const* d_in, const int* in_sizes, int n_in,
                              void* d_out, int out_size, void* d_ws, size_t ws_size,
                              hipStream_t stream) {
    const float* emb   = (const float*)d_in[0];
    const float* g1    = (const float*)d_in[1];
    const float* be1   = (const float*)d_in[2];
    const float* WQ    = (const float*)d_in[3];
    const float* WK    = (const float*)d_in[4];
    const float* WV    = (const float*)d_in[5];
    const float* Wp    = (const float*)d_in[6];
    const float* bproj = (const float*)d_in[7];
    const float* g2    = (const float*)d_in[8];
    const float* be2   = (const float*)d_in[9];
    const float* Wr    = (const float*)d_in[10];
    const float* br    = (const float*)d_in[11];
    const float* W1    = (const float*)d_in[12];
    const float* b1e   = (const float*)d_in[13];
    const float* W2    = (const float*)d_in[14];
    const float* b2e   = (const float*)d_in[15];
    float* out = (float*)d_out;
    char* ws = (char*)d_ws;

    u16*   hbuf = (u16*)  (ws + H_OFF);
    u16*   xh   = (u16*)  (ws + XH_OFF);
    u16*   xl   = (u16*)  (ws + XL_OFF);
    float* Qf   = (float*)(ws + QF_OFF);
    float* Kf   = (float*)(ws + KF_OFF);
    float* Vf   = (float*)(ws + VF_OFF);
    u16*   Qh   = (u16*)  (ws + QH_OFF);
    u16*   Ql   = (u16*)  (ws + QL_OFF);
    u16*   Kh   = (u16*)  (ws + KH_OFF);
    u16*   Kl   = (u16*)  (ws + KL_OFF);
    u16*   Vh   = (u16*)  (ws + VH_OFF);
    u16*   Vl   = (u16*)  (ws + VL_OFF);
    u16*   Ah   = (u16*)  (ws + AH_OFF);
    u16*   Al   = (u16*)  (ws + AL_OFF);
    float* emb2 = (float*)(ws + E2_OFF);
    float* y32  = (float*)(ws + Y32_OFF);
    u16*   ybf  = (u16*)  (ws + YBF_OFF);
    float* moe  = (float*)(ws + MOE_OFF);
    float* wbuf = (float*)(ws + W_OFF);
    int*   cnt  = (int*)  (ws + CNT_OFF);
    int*   list = (int*)  (ws + LIST_OFF);
    float* gate = (float*)(ws + GATE_OFF);

    hipMemsetAsync(moe, 0, (size_t)TSEQ * DMOD * sizeof(float), stream);
    hipMemsetAsync(cnt, 0, 8 * sizeof(int), stream);

    ln1_kernel<<<TSEQ, 256, 0, stream>>>(emb, g1, be1, xh, xl);
    qkv_kernel<<<dim3(16, 16, 3), 256, 0, stream>>>(xh, xl, WQ, WK, WV, Qf, Kf, Vf);
    rope_cvt_kernel<<<2048, 256, 0, stream>>>(Qf, Kf, Vf, Qh, Ql, Kh, Kl, Vh, Vl);
    attn_kernel<<<dim3(16, 16), 256, 0, stream>>>(Qh, Ql, Kh, Kl, Vh, Vl, Ah, Al);
    proj_kernel<<<dim3(16, 16), 256, 0, stream>>>(Ah, Al, Wp, emb, bproj, emb2);
    ln2_kernel<<<TSEQ, 256, 0, stream>>>(emb2, g2, be2, y32, ybf);
    router_kernel<<<TSEQ, 64, 0, stream>>>(y32, Wr, br, wbuf, cnt, list, gate);
    moe1_kernel<<<dim3(64, 8), 256, 0, stream>>>(ybf, W1, b1e, cnt, list, hbuf);
    moe2_kernel<<<dim3(16, 2, 8), 256, 0, stream>>>(hbuf, W2, b2e, cnt, list, gate, moe);
    combine_kernel<<<1024, 256, 0, stream>>>(emb2, moe, out);
    aux_kernel<<<1, 64, 0, stream>>>(wbuf, out);
}